// Round 1
// baseline (603.557 us; speedup 1.0000x reference)
//
#include <hip/hip_runtime.h>
#include <stdint.h>

#define B_    64
#define CIN   64
#define L_IN  16384
#define COUT  128
#define K_    7
#define LPAD  3
#define LP    (L_IN + 2*LPAD)   // 16390 packed positions per (b)
#define LPA   16416             // padded row stride for A (room for OOB reads)
#define LOUT  8189              // pooled output length
#define NTERMS 448
#define TOUT  8                 // pooled outputs per thread
#define CO_PER_BLK 16

// ---------------- pack A: sign bits of I along Cin into uint64 ----------------
// A[b][l] for l in [0,16390): bit ci = 1 iff value < 0. Pad positions (value -1.0) = all ones.
__global__ __launch_bounds__(256) void pack_A(const float* __restrict__ I,
                                              uint64_t* __restrict__ A) {
    int b     = blockIdx.x >> 4;     // 16 blocks per b
    int chunk = blockIdx.x & 15;
    int t     = threadIdx.x;
    int l0    = chunk * 1024 + t * 4;          // interior position in [0,16384)
    const float* Ib = I + (size_t)b * CIN * L_IN + l0;
    uint64_t acc0 = 0, acc1 = 0, acc2 = 0, acc3 = 0;
#pragma unroll
    for (int ci = 0; ci < CIN; ++ci) {
        float4 v = *(const float4*)(Ib + (size_t)ci * L_IN);
        acc0 |= (uint64_t)(__float_as_uint(v.x) >> 31) << ci;
        acc1 |= (uint64_t)(__float_as_uint(v.y) >> 31) << ci;
        acc2 |= (uint64_t)(__float_as_uint(v.z) >> 31) << ci;
        acc3 |= (uint64_t)(__float_as_uint(v.w) >> 31) << ci;
    }
    uint64_t* Ab = A + (size_t)b * LPA + (LPAD + l0);
    Ab[0] = acc0; Ab[1] = acc1; Ab[2] = acc2; Ab[3] = acc3;
    // pad columns: l in {0,1,2, 16387,16388,16389} -> sign(-1.0) = -1 -> all ones
    if (chunk == 0 && t < 6) {
        int l = (t < 3) ? t : (L_IN + t);      // t=3..5 -> 16387..16389
        A[(size_t)b * LPA + l] = ~0ULL;
    }
}

// ---------------- pack W: sign bits along Cin into uint64, layout [co][k] ----------------
__global__ __launch_bounds__(256) void pack_W(const float* __restrict__ W,
                                              uint64_t* __restrict__ Bp) {
    int idx = blockIdx.x * 256 + threadIdx.x;
    if (idx >= COUT * K_) return;
    int co = idx / K_, k = idx - co * K_;
    uint64_t acc = 0;
#pragma unroll
    for (int ci = 0; ci < CIN; ++ci) {
        uint32_t s = __float_as_uint(W[(size_t)co * CIN * K_ + ci * K_ + k]) >> 31;
        acc |= (uint64_t)s << ci;
    }
    Bp[idx] = acc;
}

// ---------------- main: binary conv + maxpool(7, stride 2) + threshold ----------------
__global__ __launch_bounds__(256) void bconv_pool_thresh(
    const uint64_t* __restrict__ A, const uint64_t* __restrict__ Bp,
    const float* __restrict__ tp_, const float* __restrict__ tm_,
    const float* __restrict__ ps_, const float* __restrict__ ms_,
    float* __restrict__ out)
{
    const int cg = blockIdx.x;   // 0..7   co group
    const int lc = blockIdx.y;   // 0..3   l chunk
    const int b  = blockIdx.z;   // 0..63
    const int t  = threadIdx.x;
    const int out0 = lc * 2048 + t * TOUT;     // first pooled output this thread owns

    // A window this thread needs: conv positions [2*out0, 2*out0+2T+4], each uses 7 A's
    const uint64_t* Ab = A + (size_t)b * LPA + 2 * out0;
    uint64_t a[2 * TOUT + 11];
#pragma unroll
    for (int j = 0; j < 2 * TOUT + 11; ++j) a[j] = Ab[j];

#pragma unroll 1
    for (int ci_ = 0; ci_ < CO_PER_BLK; ++ci_) {
        const int co = cg * CO_PER_BLK + ci_;
        const uint64_t* Bco = Bp + co * K_;
        const uint64_t w0 = Bco[0], w1 = Bco[1], w2 = Bco[2], w3 = Bco[3],
                       w4 = Bco[4], w5 = Bco[5], w6 = Bco[6];

        // s[j] = sum_k popcount(A[j+k] ^ B[k])  (conv = 448 - 2*s)
        int s[2 * TOUT + 5];
#pragma unroll
        for (int j = 0; j < 2 * TOUT + 5; ++j) {
            int acc;
            acc  = __popcll(a[j + 0] ^ w0);
            acc += __popcll(a[j + 1] ^ w1);
            acc += __popcll(a[j + 2] ^ w2);
            acc += __popcll(a[j + 3] ^ w3);
            acc += __popcll(a[j + 4] ^ w4);
            acc += __popcll(a[j + 5] ^ w5);
            acc += __popcll(a[j + 6] ^ w6);
            s[j] = acc;
        }

        // max-pool window 7 stride 2 on conv == min on s; pairwise-min sharing
        int p[TOUT + 2];
#pragma unroll
        for (int i = 0; i < TOUT + 2; ++i) p[i] = min(s[2 * i], s[2 * i + 1]);

        const float tp = tp_[co], tm = tm_[co], ps = ps_[co], ms = ms_[co];
        float* op = out + ((size_t)(b * COUT + co)) * LOUT + out0;
#pragma unroll
        for (int o = 0; o < TOUT; ++o) {
            int smin = min(min(p[o], p[o + 1]), min(p[o + 2], s[2 * o + 6]));
            float pooled = (float)(NTERMS - 2 * smin);
            float pos = pooled > tp ? ps : -ps;
            float neg = pooled > tm ? ms : -ms;
            float r   = (pooled >= 0.0f) ? pos : neg;
            if (out0 + o < LOUT) op[o] = r;
        }
    }
}

extern "C" void kernel_launch(void* const* d_in, const int* in_sizes, int n_in,
                              void* d_out, int out_size, void* d_ws, size_t ws_size,
                              hipStream_t stream) {
    const float* I  = (const float*)d_in[0];
    const float* W  = (const float*)d_in[1];
    const float* tp = (const float*)d_in[2];
    const float* tm = (const float*)d_in[3];
    const float* ps = (const float*)d_in[4];
    const float* ms = (const float*)d_in[5];
    float* out = (float*)d_out;

    uint64_t* A  = (uint64_t*)d_ws;
    uint64_t* Bp = (uint64_t*)((char*)d_ws + (size_t)B_ * LPA * sizeof(uint64_t));

    hipLaunchKernelGGL(pack_A, dim3(B_ * 16), dim3(256), 0, stream, I, A);
    hipLaunchKernelGGL(pack_W, dim3((COUT * K_ + 255) / 256), dim3(256), 0, stream, W, Bp);
    hipLaunchKernelGGL(bconv_pool_thresh, dim3(8, 4, B_), dim3(256), 0, stream,
                       A, Bp, tp, tm, ps, ms, out);
}

// Round 2
// 598.516 us; speedup vs baseline: 1.0084x; 1.0084x over previous
//
#include <hip/hip_runtime.h>
#include <stdint.h>

#define B_    64
#define CIN   64
#define L_IN  16384
#define COUT  128
#define K_    7
#define LPAD  3
#define LP    (L_IN + 2*LPAD)   // 16390 packed positions per (b)
#define LPA   16416             // padded row stride for A
#define LOUT  8189              // pooled output length
#define NTERMS 448
#define TOUT  8                 // pooled outputs per thread
#define CO_PER_BLK 16

// ---------------- pack A: sign bits of I along Cin into uint64 ----------------
// A[b][l]: bit ci = 1 iff value < 0. Pad positions (value -1.0) = all ones.
__global__ __launch_bounds__(256) void pack_A(const float* __restrict__ I,
                                              uint64_t* __restrict__ A) {
    int b     = blockIdx.x >> 4;     // 16 blocks per b
    int chunk = blockIdx.x & 15;
    int t     = threadIdx.x;
    int l0    = chunk * 1024 + t * 4;
    const uint32_t* Ib = (const uint32_t*)(I + (size_t)b * CIN * L_IN + l0);
    uint32_t lo0 = 0, lo1 = 0, lo2 = 0, lo3 = 0;
    uint32_t hi0 = 0, hi1 = 0, hi2 = 0, hi3 = 0;
#pragma unroll 8
    for (int ci = 0; ci < 32; ++ci) {
        uint4 v = *(const uint4*)(Ib + (size_t)ci * L_IN);
        lo0 |= (v.x >> 31) << ci;
        lo1 |= (v.y >> 31) << ci;
        lo2 |= (v.z >> 31) << ci;
        lo3 |= (v.w >> 31) << ci;
    }
#pragma unroll 8
    for (int ci = 0; ci < 32; ++ci) {
        uint4 v = *(const uint4*)(Ib + (size_t)(ci + 32) * L_IN);
        hi0 |= (v.x >> 31) << ci;
        hi1 |= (v.y >> 31) << ci;
        hi2 |= (v.z >> 31) << ci;
        hi3 |= (v.w >> 31) << ci;
    }
    uint64_t* Ab = A + (size_t)b * LPA + (LPAD + l0);
    Ab[0] = ((uint64_t)hi0 << 32) | lo0;
    Ab[1] = ((uint64_t)hi1 << 32) | lo1;
    Ab[2] = ((uint64_t)hi2 << 32) | lo2;
    Ab[3] = ((uint64_t)hi3 << 32) | lo3;
    // pad columns: l in {0,1,2, 16387,16388,16389} -> sign(-1.0) -> all ones
    if (chunk == 0 && t < 6) {
        int l = (t < 3) ? t : (L_IN + t);
        A[(size_t)b * LPA + l] = ~0ULL;
    }
}

// ---------------- pack W ----------------
__global__ __launch_bounds__(256) void pack_W(const float* __restrict__ W,
                                              uint64_t* __restrict__ Bp) {
    int idx = blockIdx.x * 256 + threadIdx.x;
    if (idx >= COUT * K_) return;
    int co = idx / K_, k = idx - co * K_;
    uint64_t acc = 0;
#pragma unroll
    for (int ci = 0; ci < CIN; ++ci) {
        uint32_t s = __float_as_uint(W[(size_t)co * CIN * K_ + ci * K_ + k]) >> 31;
        acc |= (uint64_t)s << ci;
    }
    Bp[idx] = acc;
}

// ---------------- main: binary conv + maxpool(7,2) + threshold ----------------
__global__ __launch_bounds__(256, 4) void bconv_pool_thresh(
    const uint64_t* __restrict__ A, const uint64_t* __restrict__ Bp,
    const float* __restrict__ tp_, const float* __restrict__ tm_,
    const float* __restrict__ ps_, const float* __restrict__ ms_,
    float* __restrict__ out)
{
    const int cg = blockIdx.x;   // 0..7   co group
    const int lc = blockIdx.y;   // 0..3   l chunk
    const int b  = blockIdx.z;   // 0..63
    const int t  = threadIdx.x;
    int out0 = lc * 2048 + t * TOUT;
    // clamp so every lane writes TOUT valid outputs (duplicates write identical values)
    if (out0 > LOUT - TOUT) out0 = LOUT - TOUT;

    // A window: conv positions [2*out0 .. 2*out0+20], each uses a[j..j+6] -> 27 words
    const uint64_t* Ab = A + (size_t)b * LPA + 2 * out0;
    uint64_t a[2 * TOUT + 11];
#pragma unroll
    for (int j = 0; j < 2 * TOUT + 11; ++j) a[j] = Ab[j];

#pragma unroll 1
    for (int ci_ = 0; ci_ < CO_PER_BLK; ++ci_) {
        const int co = cg * CO_PER_BLK + ci_;
        const uint64_t* Bco = Bp + co * K_;
        const uint64_t w0 = Bco[0], w1 = Bco[1], w2 = Bco[2], w3 = Bco[3],
                       w4 = Bco[4], w5 = Bco[5], w6 = Bco[6];

        // s[j] = sum_k popcount(a[j+k] ^ w[k]);  conv = 448 - 2*s
        int s[2 * TOUT + 5];
#pragma unroll
        for (int j = 0; j < 2 * TOUT + 5; ++j) {
            int acc;
            acc  = __popcll(a[j + 0] ^ w0);
            acc += __popcll(a[j + 1] ^ w1);
            acc += __popcll(a[j + 2] ^ w2);
            acc += __popcll(a[j + 3] ^ w3);
            acc += __popcll(a[j + 4] ^ w4);
            acc += __popcll(a[j + 5] ^ w5);
            acc += __popcll(a[j + 6] ^ w6);
            s[j] = acc;
        }

        int p[TOUT + 2];
#pragma unroll
        for (int i = 0; i < TOUT + 2; ++i) p[i] = min(s[2 * i], s[2 * i + 1]);

        // epilogue in s-domain: pooled = 448-2*smin; pooled>tp <=> smin < (448-tp)/2
        const float ftp = (448.0f - tp_[co]) * 0.5f;
        const float ftm = (448.0f - tm_[co]) * 0.5f;
        const float ps = ps_[co], ms = ms_[co];
        float* op = out + ((size_t)(b * COUT + co)) * LOUT + out0;
#pragma unroll
        for (int o = 0; o < TOUT; ++o) {
            int smin = min(min(p[o], p[o + 1]), min(p[o + 2], s[2 * o + 6]));
            float sf  = (float)smin;
            float pos = sf < ftp ? ps : -ps;
            float neg = sf < ftm ? ms : -ms;
            op[o] = (sf <= 224.0f) ? pos : neg;
        }
    }
}

extern "C" void kernel_launch(void* const* d_in, const int* in_sizes, int n_in,
                              void* d_out, int out_size, void* d_ws, size_t ws_size,
                              hipStream_t stream) {
    const float* I  = (const float*)d_in[0];
    const float* W  = (const float*)d_in[1];
    const float* tp = (const float*)d_in[2];
    const float* tm = (const float*)d_in[3];
    const float* ps = (const float*)d_in[4];
    const float* ms = (const float*)d_in[5];
    float* out = (float*)d_out;

    uint64_t* A  = (uint64_t*)d_ws;
    uint64_t* Bp = (uint64_t*)((char*)d_ws + (size_t)B_ * LPA * sizeof(uint64_t));

    hipLaunchKernelGGL(pack_A, dim3(B_ * 16), dim3(256), 0, stream, I, A);
    hipLaunchKernelGGL(pack_W, dim3((COUT * K_ + 255) / 256), dim3(256), 0, stream, W, Bp);
    hipLaunchKernelGGL(bconv_pool_thresh, dim3(8, 4, B_), dim3(256), 0, stream,
                       A, Bp, tp, tm, ps, ms, out);
}